// Round 4
// baseline (152.181 us; speedup 1.0000x reference)
//
#include <hip/hip_runtime.h>
#include <hip/hip_bf16.h>

// GAT layer, MI355X. B=32, N=512, Fin=256, F=64, H=8.
// Round-4: inputs fp32 (probe-confirmed R3: flag=0 path ran, no NaN),
// OUTPUT fp32 (R3's absmax 0.834 == bf16-pair-in-fp32-buffer signature:
// word k decodes ~ref[2k+1], max|ref[2k]-ref[2k+1]| ~ 0.83). Fused: one
// block per (b,h); h-tile bf16 in LDS; MFMA for x@W and P@h; softmax
// normalization commuted past PV (out_i = sum_j p_ij h_j / sum_j p_ij).

#define ALPHA 0.2f

typedef __bf16 bf16x8 __attribute__((ext_vector_type(8)));
typedef __bf16 bf16x4 __attribute__((ext_vector_type(4)));
typedef float  f32x4  __attribute__((ext_vector_type(4)));

#define HT_STRIDE 520   // 512 + 8: break power-of-2 LDS stride
#define WT_STRIDE 264   // 256 + 8

struct Smem {
    __bf16 hT[64][HT_STRIDE];   // h^T tile [f][j]      66,560 B
    __bf16 WT[64][WT_STRIDE];   // W cols [n][k]        33,792 B
    float  ssrc[512], sdst[512], rsum[512];          //  6,144 B
    float  asrc[64], adst[64];                       //    512 B
};                                                   // ~107 KB < 160 KB

// ---- dtype-generic 8-element loaders --------------------------------------
__device__ inline bf16x8 ld8(const __bf16* p) { return *(const bf16x8*)p; }
__device__ inline bf16x8 ld8(const float* p) {
    float4 a0 = *(const float4*)p;
    float4 a1 = *(const float4*)(p + 4);
    bf16x8 r;
    r[0]=(__bf16)a0.x; r[1]=(__bf16)a0.y; r[2]=(__bf16)a0.z; r[3]=(__bf16)a0.w;
    r[4]=(__bf16)a1.x; r[5]=(__bf16)a1.y; r[6]=(__bf16)a1.z; r[7]=(__bf16)a1.w;
    return r;
}
__device__ inline void ld8f(const __bf16* p, float* o) {
    bf16x8 v = *(const bf16x8*)p;
    #pragma unroll
    for (int u = 0; u < 8; ++u) o[u] = (float)v[u];
}
__device__ inline void ld8f(const float* p, float* o) {
    float4 a0 = *(const float4*)p;
    float4 a1 = *(const float4*)(p + 4);
    o[0]=a0.x; o[1]=a0.y; o[2]=a0.z; o[3]=a0.w;
    o[4]=a1.x; o[5]=a1.y; o[6]=a1.z; o[7]=a1.w;
}

// ---- fused body, templated on input dtype ---------------------------------
template <typename T>
__device__ void gat_body(const T* __restrict__ x, const T* __restrict__ adj,
                         const T* __restrict__ W, const T* __restrict__ a,
                         float* __restrict__ out, Smem& sm,
                         int b, int h, int tid) {
    const int wave = tid >> 6, lane = tid & 63;
    const int quad = lane >> 4, col = lane & 15;

    // stage 0: stage a (fp32) and W[:, h*64..h*64+64) (bf16) into LDS
    if (tid < 128) {
        float v = (float)a[h * 128 + tid];
        if (tid < 64) sm.asrc[tid] = v; else sm.adst[tid - 64] = v;
    }
    {
        int c = tid & 63, k0 = tid >> 6;             // 64 cols x 8 k-lanes
        #pragma unroll 4
        for (int t = 0; t < 32; ++t) {
            int k = k0 + t * 8;
            sm.WT[c][k] = (__bf16)(float)W[(long)k * 512 + h * 64 + c];
        }
    }
    __syncthreads();

    // stage 1: h = x[b] @ W[:,h-block] -> hT[f][j]  (MFMA 16x16x32 bf16)
    {
        const T* xb = x + (long)b * 512 * 256;
        f32x4 acc[4][4] = {};
        for (int ks = 0; ks < 8; ++ks) {             // K = 256
            int k0 = ks * 32 + quad * 8;
            bf16x8 av[4], bv[4];
            #pragma unroll
            for (int it = 0; it < 4; ++it)           // A[m=col][k=quad*8+u]
                av[it] = ld8(xb + (long)(wave * 64 + it * 16 + col) * 256 + k0);
            #pragma unroll
            for (int nt = 0; nt < 4; ++nt)           // B[k][n=col]
                bv[nt] = *(const bf16x8*)(&sm.WT[nt * 16 + col][k0]);
            #pragma unroll
            for (int it = 0; it < 4; ++it)
                #pragma unroll
                for (int nt = 0; nt < 4; ++nt)
                    acc[it][nt] = __builtin_amdgcn_mfma_f32_16x16x32_bf16(av[it], bv[nt], acc[it][nt], 0, 0, 0);
        }
        #pragma unroll
        for (int it = 0; it < 4; ++it)
            #pragma unroll
            for (int nt = 0; nt < 4; ++nt) {
                int f = nt * 16 + col;               // C/D: col=f, row=node
                int j = wave * 64 + it * 16 + quad * 4;
                bf16x4 pk = { (__bf16)acc[it][nt][0], (__bf16)acc[it][nt][1],
                              (__bf16)acc[it][nt][2], (__bf16)acc[it][nt][3] };
                *(bf16x4*)(&sm.hT[f][j]) = pk;
            }
    }
    __syncthreads();

    // stage 2: s_src[j], s_dst[j] = h_j . a (fp32 accum)
    {
        float as = 0.f, ad = 0.f;
        #pragma unroll 8
        for (int f = 0; f < 64; ++f) {
            float v = (float)sm.hT[f][tid];
            as += v * sm.asrc[f];
            ad += v * sm.adst[f];
        }
        sm.ssrc[tid] = as;
        sm.sdst[tid] = ad;
    }
    __syncthreads();

    // stage 3: fused P-gen + P@h MFMA + online row sums
    {
        float si[4], sacc[4] = {0.f, 0.f, 0.f, 0.f};
        const T* arow[4];
        #pragma unroll
        for (int it = 0; it < 4; ++it) {
            int i = wave * 64 + it * 16 + col;       // A-row m = lane&15
            si[it]   = sm.ssrc[i];
            arow[it] = adj + ((long)(b * 512 + i)) * 512;
        }
        f32x4 acc[4][4] = {};
        for (int ks = 0; ks < 16; ++ks) {            // K = 512 neighbors
            int j0 = ks * 32 + quad * 8;
            f32x4 s0 = *(const f32x4*)&sm.sdst[j0];
            f32x4 s1 = *(const f32x4*)&sm.sdst[j0 + 4];
            float sd[8] = {s0[0],s0[1],s0[2],s0[3],s1[0],s1[1],s1[2],s1[3]};
            bf16x8 P[4];
            #pragma unroll
            for (int it = 0; it < 4; ++it) {
                float am[8];
                ld8f(arow[it] + j0, am);
                #pragma unroll
                for (int u = 0; u < 8; ++u) {
                    float e = si[it] + sd[u];
                    e = e > 0.f ? e : ALPHA * e;
                    float p = (am[u] > 0.f) ? __expf(e) : 0.f;  // unnormalized
                    __bf16 pb = (__bf16)p;
                    sacc[it] += (float)pb;           // sum the rounded p
                    P[it][u] = pb;
                }
            }
            #pragma unroll
            for (int nt = 0; nt < 4; ++nt) {
                bf16x8 bv = *(const bf16x8*)(&sm.hT[nt * 16 + col][j0]);
                #pragma unroll
                for (int it = 0; it < 4; ++it)
                    acc[it][nt] = __builtin_amdgcn_mfma_f32_16x16x32_bf16(P[it], bv, acc[it][nt], 0, 0, 0);
            }
        }
        // fold per-quad partial row sums (same i lives in all 4 quads)
        #pragma unroll
        for (int it = 0; it < 4; ++it) {
            float s = sacc[it];
            s += __shfl_xor(s, 16);
            s += __shfl_xor(s, 32);
            if (quad == 0) sm.rsum[wave * 64 + it * 16 + col] = s;
        }
        __syncthreads();
        // epilogue: normalize, store fp32
        #pragma unroll
        for (int it = 0; it < 4; ++it)
            #pragma unroll
            for (int r = 0; r < 4; ++r) {
                int i = wave * 64 + it * 16 + quad * 4 + r;   // C/D row
                float s = sm.rsum[i];
                float inv = (s > 0.f) ? 1.0f / s : 0.f;
                float* orow = out + ((long)(b * 512 + i)) * 512 + h * 64;
                #pragma unroll
                for (int nt = 0; nt < 4; ++nt)
                    orow[nt * 16 + col] = acc[it][nt][r] * inv;
            }
    }
}

// ---- dtype probe: adj is exactly {0,1} ------------------------------------
// fp32 words: low16 always 0x0000. bf16 pairs: low16 in {0x0000, 0x3F80},
// ~50% hit rate -> ballot over 64 words is decisive.
__global__ void k_probe(const unsigned int* __restrict__ adjw,
                        int* __restrict__ flag) {
    unsigned int v = adjw[threadIdx.x];
    unsigned long long m = __ballot((v & 0xFFFFu) == 0x3F80u);
    if (threadIdx.x == 0) flag[0] = (m != 0ull) ? 1 : 0;
}

__global__ __launch_bounds__(512, 1) void k_gat(const void* __restrict__ x,
                                                const void* __restrict__ adj,
                                                const void* __restrict__ W,
                                                const void* __restrict__ a,
                                                float* __restrict__ out,
                                                const int* __restrict__ flag) {
    __shared__ Smem sm;
    const int h = blockIdx.x, b = blockIdx.y, tid = threadIdx.x;
    if (*flag)   // wave-uniform branch; inputs are bf16
        gat_body<__bf16>((const __bf16*)x, (const __bf16*)adj,
                         (const __bf16*)W, (const __bf16*)a, out, sm, b, h, tid);
    else         // inputs are fp32
        gat_body<float>((const float*)x, (const float*)adj,
                        (const float*)W, (const float*)a, out, sm, b, h, tid);
}

// ---- launch ---------------------------------------------------------------
extern "C" void kernel_launch(void* const* d_in, const int* in_sizes, int n_in,
                              void* d_out, int out_size, void* d_ws, size_t ws_size,
                              hipStream_t stream) {
    const void* x   = d_in[0];        // (32,512,256) fp32
    const void* adj = d_in[1];        // (32,512,512) fp32, values {0,1}
    const void* W   = d_in[2];        // (256,512)    fp32
    const void* a   = d_in[3];        // (8,128)      fp32
    float* out = (float*)d_out;       // (32,512,512) fp32
    int* flag = (int*)d_ws;           // 4 bytes of scratch

    k_probe<<<1, 64, 0, stream>>>((const unsigned int*)adj, flag);
    k_gat<<<dim3(8, 32), 512, 0, stream>>>(x, adj, W, a, out, flag);
}